// Round 3
// baseline (380.654 us; speedup 1.0000x reference)
//
#include <hip/hip_runtime.h>

// NaryDecoderCell: B=2048, C=256, HS=512, H2=1024, D=8
// pack(bf16, K-concat) -> gemm_fused (K=1280, split-N epilogue at K=256)
//   -> GRU pointwise (+probs) -> split-K gemm_bt(hc) -> reduce+tanh -> h

#define B_   2048
#define C_   256
#define HS_  512
#define H2_  1024
#define G3_  3072
#define D_   8
#define NG_  24576
#define KF_  1280          // 256 + 1024 fused K

typedef __attribute__((ext_vector_type(8))) short bfrag;   // 8 x bf16
typedef __attribute__((ext_vector_type(4))) float f32x4;   // MFMA C/D

static __device__ __forceinline__ unsigned short f2bf(float f) {
  unsigned u = __float_as_uint(f);
  u = (u + 0x7FFFu + ((u >> 16) & 1u)) >> 16;   // RTNE
  return (unsigned short)u;
}
static __device__ __forceinline__ float bf2f(unsigned short s) {
  return __uint_as_float(((unsigned)s) << 16);
}
static __device__ __forceinline__ float fast_sigmoid(float x) {
  return 1.f / (1.f + __expf(-x));
}
static __device__ __forceinline__ float fast_tanh(float x) {
  return 1.f - 2.f / (__expf(2.f * x) + 1.f);
}

__device__ __forceinline__ void load16(const void* g, void* l) {
  __builtin_amdgcn_global_load_lds((const __attribute__((address_space(1))) void*)g,
                                   (__attribute__((address_space(3))) void*)l,
                                   16, 0, 0);
}

// ---------------- pack: f32 -> bf16, K-concatenated layouts ----------------
// A  [2048][1280] = [x(256) | ph(512) | enc(512)]
// Bf [24576][1280] = [W_ih row(256) | W_hh row(1024)]
// BWh[512][8192]   = W_h permuted: Bt[kk][d*1024+h]
__global__ __launch_bounds__(256) void pack_kernel(
    const float* __restrict__ x, const float* __restrict__ ph,
    const float* __restrict__ enc, const float* __restrict__ Wih,
    const float* __restrict__ Whh, const float* __restrict__ Wh,
    unsigned short* __restrict__ A, unsigned short* __restrict__ Bf,
    unsigned short* __restrict__ BWh)
{
  const long long total4 = 38273024LL / 4;
  const long long stride = (long long)gridDim.x * blockDim.x;
  for (long long i = (long long)blockIdx.x * blockDim.x + threadIdx.x;
       i < total4; i += stride) {
    long long o = i * 4;
    const float* src;
    unsigned short* dst;
    if (o < 2621440) {                       // A
      unsigned rel = (unsigned)o;
      unsigned b = rel / 1280u, c = rel % 1280u;
      if (c < 256) src = x + (size_t)b * 256 + c;
      else if (c < 768) src = ph + (size_t)b * 512 + (c - 256);
      else src = enc + (size_t)b * 512 + (c - 768);
      dst = A + rel;
    } else if (o < 34078720) {               // Bf
      unsigned rel = (unsigned)(o - 2621440);
      unsigned g = rel / 1280u, c = rel % 1280u;
      src = (c < 256) ? (Wih + (size_t)g * 256 + c)
                      : (Whh + (size_t)g * 1024 + (c - 256));
      dst = Bf + rel;
    } else {                                 // BWh permute
      unsigned rel = (unsigned)(o - 34078720);
      unsigned kk = rel >> 13;
      unsigned r2 = rel & 8191;
      unsigned d = r2 >> 10, hh = r2 & 1023;
      src = Wh + ((size_t)d * 524288 + (size_t)kk * 1024 + hh);
      dst = BWh + rel;
    }
    float4 v = *(const float4*)src;
    ushort4 w;
    w.x = f2bf(v.x); w.y = f2bf(v.y); w.z = f2bf(v.z); w.w = f2bf(v.w);
    *(ushort4*)dst = w;
  }
}

// ---------------- fused 256x256 GEMM, K=1280, distance-2 prefetch ----------
// Gsum[b, dg] = gi+gh for r,z columns; = h_n for n columns.
// In[b, d*1024+h] = i_n (n-gate partial at K=256), dumped mid-loop.
__global__ __launch_bounds__(512, 2) void gemm_fused(
    const unsigned short* __restrict__ A, const unsigned short* __restrict__ Bt,
    unsigned short* __restrict__ Gsum, unsigned short* __restrict__ In)
{
  extern __shared__ char lds[];    // A: 2buf x 2half x 16KB | B: same = 128 KiB
  const int K = KF_, N = NG_;
  const int t = threadIdx.x;
  const int wave = t >> 6, lane = t & 63;
  const int wr = wave >> 2, wc = wave & 3;
  const int la = lane & 15, ls = lane >> 4;

  // T1 bijective XCD swizzle (nwg=768, %8==0), column-major decode (gridY=8)
  const int q8 = gridDim.x >> 3;
  const int orig = blockIdx.x;
  const int swz = (orig & 7) * q8 + (orig >> 3);
  const int brow = (swz & 7) << 8;
  const int bcol = (swz >> 3) << 8;
  const int nT = K >> 6;                     // 20
  const bool isN = ((bcol % G3_) >= 2048);

  const int srr = t >> 3;
  const int ssc = ((t & 7) ^ ((t >> 3) & 7)) << 3;   // pre-swizzled src col

  auto stageA = [&](int kt, int buf, int hf) {
    const unsigned short* src = A + (size_t)(brow + hf * 128 + srr) * K + kt * 64 + ssc;
    char* dst = lds + buf * 32768 + hf * 16384 + t * 16;
    load16(src, dst);
    load16(src + (size_t)64 * K, dst + 8192);
  };
  auto stageB = [&](int kt, int buf, int hf) {
    const unsigned short* src = Bt + (size_t)(bcol + hf * 128 + srr) * K + kt * 64 + ssc;
    char* dst = lds + 65536 + buf * 32768 + hf * 16384 + t * 16;
    load16(src, dst);
    load16(src + (size_t)64 * K, dst + 8192);
  };

  // prologue: tile0 -> buf0, tile1 -> buf1; wait tile0 landed (8 still out)
  stageA(0, 0, 0); stageA(0, 0, 1); stageB(0, 0, 0); stageB(0, 0, 1);
  stageA(1, 1, 0); stageA(1, 1, 1); stageB(1, 1, 0); stageB(1, 1, 1);
  asm volatile("s_waitcnt vmcnt(8)" ::: "memory");
  __builtin_amdgcn_s_barrier();

  f32x4 acc[8][4];
#pragma unroll
  for (int m = 0; m < 8; ++m)
#pragma unroll
    for (int n = 0; n < 4; ++n) acc[m][n] = (f32x4){0.f, 0.f, 0.f, 0.f};

  const int sw = (la & 7) << 4;
  const int c0 = (ls << 4) ^ sw;             // swizzled k0 byte col

  const int orow = brow + wr * 128 + ls * 4;
  const int ocol = bcol + wc * 64 + la;

#pragma unroll 1
  for (int kt = 0; kt < nT; ++kt) {
    const int buf = kt & 1;
    const int kt2 = (kt + 2 < nT) ? kt + 2 : nT - 1;
    const char* ab = lds + buf * 32768 + wr * 16384;
    const char* bb = lds + 65536 + buf * 32768 + (wc >> 1) * 16384;
    const int brb = (wc & 1) * 64;
    bfrag a0[8], a1[8], b0[4], b1[4];

    // ---- P1: read a0(8)+b0(4); MFMA k0 m0-3
#pragma unroll
    for (int m = 0; m < 8; ++m)
      a0[m] = *(const bfrag*)(ab + (m * 16 + la) * 128 + c0);
#pragma unroll
    for (int n = 0; n < 4; ++n)
      b0[n] = *(const bfrag*)(bb + (brb + n * 16 + la) * 128 + c0);
    __builtin_amdgcn_s_barrier();
    __builtin_amdgcn_s_setprio(1);
#pragma unroll
    for (int m = 0; m < 4; ++m)
#pragma unroll
      for (int n = 0; n < 4; ++n)
        acc[m][n] = __builtin_amdgcn_mfma_f32_16x16x32_bf16(a0[m], b0[n], acc[m][n], 0, 0, 0);
    __builtin_amdgcn_s_setprio(0);
    __builtin_amdgcn_s_barrier();

    // ---- P2: read a1(8); MFMA k0 m4-7; drain lgkm (A region free after this)
#pragma unroll
    for (int m = 0; m < 8; ++m)
      a1[m] = *(const bfrag*)(ab + (m * 16 + la) * 128 + (c0 ^ 64));
    __builtin_amdgcn_s_barrier();
    __builtin_amdgcn_s_setprio(1);
#pragma unroll
    for (int m = 4; m < 8; ++m)
#pragma unroll
      for (int n = 0; n < 4; ++n)
        acc[m][n] = __builtin_amdgcn_mfma_f32_16x16x32_bf16(a0[m], b0[n], acc[m][n], 0, 0, 0);
    __builtin_amdgcn_s_setprio(0);
    asm volatile("s_waitcnt lgkmcnt(0)" ::: "memory");
    __builtin_amdgcn_s_barrier();

    // ---- P3: read b1(4); stage A(kt+2) -> current buf; MFMA k1 m0-3
#pragma unroll
    for (int n = 0; n < 4; ++n)
      b1[n] = *(const bfrag*)(bb + (brb + n * 16 + la) * 128 + (c0 ^ 64));
    stageA(kt2, buf, 0);
    stageA(kt2, buf, 1);
    __builtin_amdgcn_s_barrier();
    __builtin_amdgcn_s_setprio(1);
#pragma unroll
    for (int m = 0; m < 4; ++m)
#pragma unroll
      for (int n = 0; n < 4; ++n)
        acc[m][n] = __builtin_amdgcn_mfma_f32_16x16x32_bf16(a1[m], b1[n], acc[m][n], 0, 0, 0);
    __builtin_amdgcn_s_setprio(0);
    asm volatile("s_waitcnt lgkmcnt(0)" ::: "memory");
    __builtin_amdgcn_s_barrier();

    // ---- P4: stage B(kt+2) -> current buf; MFMA k1 m4-7; counted vmcnt
    stageB(kt2, buf, 0);
    stageB(kt2, buf, 1);
    __builtin_amdgcn_s_barrier();
    __builtin_amdgcn_s_setprio(1);
#pragma unroll
    for (int m = 4; m < 8; ++m)
#pragma unroll
      for (int n = 0; n < 4; ++n)
        acc[m][n] = __builtin_amdgcn_mfma_f32_16x16x32_bf16(a1[m], b1[n], acc[m][n], 0, 0, 0);
    __builtin_amdgcn_s_setprio(0);
    asm volatile("s_waitcnt vmcnt(8)" ::: "memory");
    __builtin_amdgcn_s_barrier();

    // ---- split boundary: n-gate blocks dump i_n (K=256 partial), reset acc
    if (isN && kt == 3) {
      const int d = bcol / G3_;
      const int jb = (bcol % G3_) - 2048 + wc * 64;
#pragma unroll
      for (int m = 0; m < 8; ++m)
#pragma unroll
        for (int n = 0; n < 4; ++n) {
#pragma unroll
          for (int r = 0; r < 4; ++r)
            In[(size_t)(orow + m * 16 + r) * 8192 + d * 1024 + jb + n * 16 + la]
                = f2bf(acc[m][n][r]);
          acc[m][n] = (f32x4){0.f, 0.f, 0.f, 0.f};
        }
    }
  }

  // epilogue: Gsum = gi+gh (rz blocks) or h_n (n blocks)
#pragma unroll
  for (int m = 0; m < 8; ++m)
#pragma unroll
    for (int n = 0; n < 4; ++n)
#pragma unroll
      for (int r = 0; r < 4; ++r)
        Gsum[(size_t)(orow + m * 16 + r) * N + (ocol + n * 16)] = f2bf(acc[m][n][r]);
}

// ---------------- 128x128 GEMM (m97 structure) — split-K hc ----------------
__global__ __launch_bounds__(256) void gemm_bt(
    const unsigned short* __restrict__ A, const unsigned short* __restrict__ Bt,
    float* __restrict__ out, int M, int N, int K, int kPerSlice)
{
  __shared__ unsigned short sA[128 * 32];
  __shared__ unsigned short sB[128 * 32];
  const int t = threadIdx.x;
  const int wave = t >> 6, lane = t & 63;
  const int wr = wave >> 1, wc = wave & 1;
  const int brow = blockIdx.y << 7;
  const int bcol = blockIdx.x << 7;
  const int kOff = blockIdx.z * kPerSlice;

  f32x4 acc[4][4];
#pragma unroll
  for (int m = 0; m < 4; m++)
#pragma unroll
    for (int n = 0; n < 4; n++) acc[m][n] = (f32x4){0.f, 0.f, 0.f, 0.f};

  const int srow = t >> 2;
  const int scol = (t & 3) << 3;
  const unsigned short* aSrc = A + (size_t)(brow + srow) * K + kOff + scol;
  const unsigned short* bSrc = Bt + (size_t)(bcol + srow) * K + kOff + scol;
  const size_t rowStep = (size_t)64 * K;
  unsigned short* dA0 = sA + wave * 512;
  unsigned short* dA1 = sA + 2048 + wave * 512;
  unsigned short* dB0 = sB + wave * 512;
  unsigned short* dB1 = sB + 2048 + wave * 512;

  const int la = lane & 15;
  const int lk = (lane >> 4) << 3;
  const int kSteps = kPerSlice >> 5;

  for (int ks = 0; ks < kSteps; ++ks) {
    load16(aSrc, dA0);
    load16(aSrc + rowStep, dA1);
    load16(bSrc, dB0);
    load16(bSrc + rowStep, dB1);
    aSrc += 32; bSrc += 32;
    __syncthreads();
    bfrag aF[4], bF[4];
#pragma unroll
    for (int m = 0; m < 4; m++)
      aF[m] = *(const bfrag*)&sA[(wr * 64 + m * 16 + la) * 32 + lk];
#pragma unroll
    for (int n = 0; n < 4; n++)
      bF[n] = *(const bfrag*)&sB[(wc * 64 + n * 16 + la) * 32 + lk];
#pragma unroll
    for (int m = 0; m < 4; m++)
#pragma unroll
      for (int n = 0; n < 4; n++)
        acc[m][n] = __builtin_amdgcn_mfma_f32_16x16x32_bf16(aF[m], bF[n], acc[m][n], 0, 0, 0);
    __syncthreads();
  }

  const int orow = brow + wr * 64 + (lane >> 4) * 4;
  const int ocol = bcol + wc * 64 + la;
  float* o = out + (size_t)blockIdx.z * ((size_t)M * N);
#pragma unroll
  for (int m = 0; m < 4; m++) {
    const int rb = orow + m * 16;
#pragma unroll
    for (int n = 0; n < 4; n++) {
      const int cb = ocol + n * 16;
#pragma unroll
      for (int r = 0; r < 4; r++)
        o[(size_t)(rb + r) * N + cb] = acc[m][n][r];
    }
  }
}

// ---------------- GRU pointwise + probs ----------------
__global__ __launch_bounds__(256) void gru_pointwise(
    const unsigned short* __restrict__ Gsum, const unsigned short* __restrict__ In,
    const float* __restrict__ b_ih, const float* __restrict__ b_hh,
    const float* __restrict__ ph, const float* __restrict__ enc,
    const float* __restrict__ W_p, const float* __restrict__ b_p,
    unsigned short* __restrict__ hn, float* __restrict__ probs)
{
  const int bd = blockIdx.x;
  const int b = bd >> 3, d = bd & 7;
  const int t = threadIdx.x;
  const size_t gbase = (size_t)b * NG_ + (size_t)d * G3_;
  const size_t ibase = (size_t)b * 8192 + (size_t)d * 1024;
  const int bb = d * G3_;
  float partial = 0.f;
#pragma unroll
  for (int i = 0; i < 2; ++i) {
    const int h = 2 * t + (i << 9);
    ushort2 gr = *(const ushort2*)(Gsum + gbase + h);
    ushort2 gz = *(const ushort2*)(Gsum + gbase + 1024 + h);
    ushort2 gn = *(const ushort2*)(Gsum + gbase + 2048 + h);
    ushort2 gi = *(const ushort2*)(In + ibase + h);
    ushort2 hv2;
#pragma unroll
    for (int j = 0; j < 2; ++j) {
      const int hj = h + j;
      float r = fast_sigmoid(bf2f(j ? gr.y : gr.x) + b_ih[bb + hj] + b_hh[bb + hj]);
      float z = fast_sigmoid(bf2f(j ? gz.y : gz.x) + b_ih[bb + 1024 + hj] + b_hh[bb + 1024 + hj]);
      float inn = bf2f(j ? gi.y : gi.x) + b_ih[bb + 2048 + hj];
      float hnn = bf2f(j ? gn.y : gn.x) + b_hh[bb + 2048 + hj];
      float nn = fast_tanh(inn + r * hnn);
      float h0 = (hj < 512) ? ph[b * 512 + hj] : enc[b * 512 + hj - 512];
      float hv = (1.f - z) * nn + z * h0;
      if (j) hv2.y = f2bf(hv); else hv2.x = f2bf(hv);
      partial += hv * W_p[d * 1024 + hj];
    }
    *(ushort2*)(hn + ibase + h) = hv2;
  }
  __shared__ float red[256];
  red[t] = partial;
  __syncthreads();
  for (int s = 128; s > 0; s >>= 1) {
    if (t < s) red[t] += red[t + s];
    __syncthreads();
  }
  if (t == 0) probs[bd] = fast_sigmoid(red[0] + b_p[d]);
}

// ---------------- reduce split-K partials + bias + tanh -> h ----------------
__global__ __launch_bounds__(256) void reduce_h_kernel(
    const float* __restrict__ part, const float* __restrict__ b_h,
    float* __restrict__ hout)
{
  const int idx = blockIdx.x * 256 + threadIdx.x;
  const int kk = idx & 511;
  float s = 0.f;
#pragma unroll
  for (int sl = 0; sl < 8; ++sl) s += part[(size_t)sl * 1048576 + idx];
  float bias = 0.f;
#pragma unroll
  for (int d = 0; d < 8; ++d) bias += b_h[d * 512 + kk];
  hout[idx] = fast_tanh(s + bias);
}

extern "C" void kernel_launch(void* const* d_in, const int* in_sizes, int n_in,
                              void* d_out, int out_size, void* d_ws, size_t ws_size,
                              hipStream_t stream) {
  const float* x   = (const float*)d_in[0];
  const float* ph  = (const float*)d_in[1];
  const float* enc = (const float*)d_in[2];
  const float* Wih = (const float*)d_in[3];
  const float* Whh = (const float*)d_in[4];
  const float* bih = (const float*)d_in[5];
  const float* bhh = (const float*)d_in[6];
  const float* Wp  = (const float*)d_in[7];
  const float* bp  = (const float*)d_in[8];
  const float* Wh  = (const float*)d_in[9];
  const float* bh  = (const float*)d_in[10];
  float* out = (float*)d_out;
  char* ws = (char*)d_ws;

  unsigned short* A    = (unsigned short*)(ws + 0);          //   5.24 MB
  unsigned short* Bf   = (unsigned short*)(ws + 5242880);    //  62.91 MB
  unsigned short* BWh  = (unsigned short*)(ws + 68157440);   //   8.39 MB
  unsigned short* Gsum = (unsigned short*)(ws + 76546048);   // 100.66 MB
  unsigned short* In   = (unsigned short*)(ws + 177209344);  //  33.55 MB
  unsigned short* hn   = (unsigned short*)(ws + 210763776);  //  33.55 MB
  float*          part = (float*)(ws + 244318208);           //  33.55 MB

  hipFuncSetAttribute((const void*)gemm_fused,
                      hipFuncAttributeMaxDynamicSharedMemorySize, 131072);

  pack_kernel<<<2048, 256, 0, stream>>>(x, ph, enc, Wih, Whh, Wh, A, Bf, BWh);

  const int nwg = (NG_ / 256) * (B_ / 256);        // 96*8 = 768, %8==0
  gemm_fused<<<nwg, 512, 131072, stream>>>(A, Bf, Gsum, In);

  gru_pointwise<<<B_ * D_, 256, 0, stream>>>(Gsum, In, bih, bhh, ph, enc, Wp, bp,
                                             hn, out + 1048576);

  dim3 g3(HS_ / 128, B_ / 128, 8);
  gemm_bt<<<g3, 256, 0, stream>>>(hn, BWh, part, B_, HS_, 8192, 1024);

  reduce_h_kernel<<<4096, 256, 0, stream>>>(part, bh, out);
}

// Round 4
// 267.289 us; speedup vs baseline: 1.4241x; 1.4241x over previous
//
#include <hip/hip_runtime.h>

// NaryDecoderCell: B=2048, C=256, HS=512, H2=1024, D=8
// pack(bf16, gate-interleaved B) -> mega_gemm (K=1280, fused GRU epilogue)
//   -> split-K gemm_bt(hc) -> reduce+tanh -> h ; probs via atomics + final sigmoid

#define B_   2048
#define C_   256
#define HS_  512
#define H2_  1024
#define G3_  3072
#define D_   8
#define NG_  24576
#define KF_  1280

typedef __attribute__((ext_vector_type(8))) short bfrag;     // 8 x bf16
typedef __attribute__((ext_vector_type(4))) float f32x4;     // MFMA C/D
typedef __attribute__((ext_vector_type(4))) unsigned short u16x4;
typedef __attribute__((ext_vector_type(2))) unsigned int u32x2;

static __device__ __forceinline__ unsigned short f2bf(float f) {
  unsigned u = __float_as_uint(f);
  u = (u + 0x7FFFu + ((u >> 16) & 1u)) >> 16;   // RTNE
  return (unsigned short)u;
}
static __device__ __forceinline__ float bf2f(unsigned short s) {
  return __uint_as_float(((unsigned)s) << 16);
}
static __device__ __forceinline__ unsigned pack2bf(float a, float b) {
  return ((unsigned)f2bf(b) << 16) | (unsigned)f2bf(a);
}
static __device__ __forceinline__ float fast_sigmoid(float x) {
  return 1.f / (1.f + __expf(-x));
}
static __device__ __forceinline__ float fast_tanh(float x) {
  return 1.f - 2.f / (__expf(2.f * x) + 1.f);
}

__device__ __forceinline__ void load16(const void* g, void* l) {
  __builtin_amdgcn_global_load_lds((const __attribute__((address_space(1))) void*)g,
                                   (__attribute__((address_space(3))) void*)l,
                                   16, 0, 0);
}

// ---------------- pack: f32 -> bf16 ----------------
// A  [2048][1280] = [x(256) | ph(512) | enc(512)]
// Bf [24576][1280], rows gate-interleaved: p = d*3072 + hb*192 + g*64 + hl
//                   maps source row d*3072 + g*1024 + hb*64 + hl
// BWh[512][8192]   = W_h permuted: Bt[kk][d*1024+h]
__global__ __launch_bounds__(256) void pack_kernel(
    const float* __restrict__ x, const float* __restrict__ ph,
    const float* __restrict__ enc, const float* __restrict__ Wih,
    const float* __restrict__ Whh, const float* __restrict__ Wh,
    unsigned short* __restrict__ A, unsigned short* __restrict__ Bf,
    unsigned short* __restrict__ BWh)
{
  const long long total4 = 38273024LL / 4;
  const long long stride = (long long)gridDim.x * blockDim.x;
  for (long long i = (long long)blockIdx.x * blockDim.x + threadIdx.x;
       i < total4; i += stride) {
    long long o = i * 4;
    const float* src;
    unsigned short* dst;
    if (o < 2621440) {                       // A
      unsigned rel = (unsigned)o;
      unsigned b = rel / 1280u, c = rel % 1280u;
      if (c < 256) src = x + (size_t)b * 256 + c;
      else if (c < 768) src = ph + (size_t)b * 512 + (c - 256);
      else src = enc + (size_t)b * 512 + (c - 768);
      dst = A + rel;
    } else if (o < 34078720) {               // Bf gate-interleaved
      unsigned rel = (unsigned)(o - 2621440);
      unsigned grow = rel / 1280u, c = rel % 1280u;
      unsigned d = grow / 3072u, rr = grow - d * 3072u;
      unsigned hbb = rr / 192u, r3 = rr - hbb * 192u;
      unsigned g = r3 >> 6, hl = r3 & 63u;
      unsigned srow = d * 3072u + g * 1024u + hbb * 64u + hl;
      src = (c < 256) ? (Wih + (size_t)srow * 256 + c)
                      : (Whh + (size_t)srow * 1024 + (c - 256));
      dst = Bf + rel;
    } else {                                 // BWh permute
      unsigned rel = (unsigned)(o - 34078720);
      unsigned kk = rel >> 13;
      unsigned r2 = rel & 8191;
      unsigned d = r2 >> 10, hh = r2 & 1023;
      src = Wh + ((size_t)d * 524288 + (size_t)kk * 1024 + hh);
      dst = BWh + rel;
    }
    float4 v = *(const float4*)src;
    ushort4 w;
    w.x = f2bf(v.x); w.y = f2bf(v.y); w.z = f2bf(v.z); w.w = f2bf(v.w);
    *(ushort4*)dst = w;
  }
}

// ---------------- mega GEMM: 256x192 tile, K=1280, fused GRU epilogue ------
// 8 waves (2M x 4N-of-48cols), BK=64. LDS: A [0,65536) 2buf x 2half x 16KB;
// B [65536,114688) 2buf x 3third x 8KB; in_lds [114688,147968) [64][260] bf16.
__global__ __launch_bounds__(512, 2) void mega_gemm(
    const unsigned short* __restrict__ A, const unsigned short* __restrict__ Bf,
    const float* __restrict__ ph, const float* __restrict__ enc,
    const float* __restrict__ bih, const float* __restrict__ bhh,
    const float* __restrict__ Wp, unsigned short* __restrict__ hn,
    float* __restrict__ pacc)
{
  extern __shared__ char lds[];
  const int t = threadIdx.x;
  const int wave = t >> 6, lane = t & 63;
  const int wr = wave >> 2, wc = wave & 3;
  const int la = lane & 15, ls = lane >> 4;

  // T1 bijective XCD swizzle (nwg=1024), column-major decode (8 row-blocks)
  const int q8 = gridDim.x >> 3;
  const int orig = blockIdx.x;
  const int swz = (orig & 7) * q8 + (orig >> 3);
  const int brow = (swz & 7) << 8;
  const int cb = swz >> 3;                   // 0..127
  const int bcol = cb * 192;
  const int d = cb >> 4, hb = cb & 15;
  const int nT = 20;

  const int srr = t >> 3;
  const int ssc = ((t & 7) ^ ((t >> 3) & 7)) << 3;   // pre-swizzled src col

  auto stageA = [&](int kt, int buf, int hf) {
    const unsigned short* src = A + (size_t)(brow + hf * 128 + srr) * KF_ + kt * 64 + ssc;
    char* dst = lds + buf * 32768 + hf * 16384 + t * 16;
    load16(src, dst);
    load16(src + (size_t)64 * KF_, dst + 8192);
  };
  auto stageB = [&](int kt, int buf, int th) {
    const unsigned short* src = Bf + (size_t)(bcol + th * 64 + srr) * KF_ + kt * 64 + ssc;
    char* dst = lds + 65536 + buf * 24576 + th * 8192 + t * 16;
    load16(src, dst);
  };

  // prologue: tile0 full (7 loads) + tile1 A halves (4); keep tile1-A in flight
  stageA(0, 0, 0); stageA(0, 0, 1);
  stageB(0, 0, 0); stageB(0, 0, 1); stageB(0, 0, 2);
  stageA(1, 1, 0); stageA(1, 1, 1);
  asm volatile("s_waitcnt vmcnt(4)" ::: "memory");
  __builtin_amdgcn_s_barrier();

  f32x4 acc[8][3];
#pragma unroll
  for (int m = 0; m < 8; ++m)
#pragma unroll
    for (int n = 0; n < 3; ++n) acc[m][n] = (f32x4){0.f, 0.f, 0.f, 0.f};

  const int c0 = (ls << 4) ^ ((la & 7) << 4);        // swizzled k0 byte col

#pragma unroll 2
  for (int kt = 0; kt < nT; ++kt) {
    const int buf = kt & 1;
    const int kt1 = (kt + 1 < nT) ? kt + 1 : nT - 1;
    const int kt2 = (kt + 2 < nT) ? kt + 2 : nT - 1;
    const char* ab = lds + buf * 32768 + wr * 16384;
    const char* bb = lds + 65536 + buf * 24576;
    bfrag a0[4], a1a[4], a1b[4], a2[4], b0[3], b1[3];

    // B row address helper pieces (row = wc*48 + n*16 + la; row&7 == la&7)
    // ---- P1: read a(m0-3,k0), a(m0-3,k1), b(k0); stage B(kt+1) thirds 0,1
#pragma unroll
    for (int m = 0; m < 4; ++m) {
      a0[m]  = *(const bfrag*)(ab + (m * 16 + la) * 128 + c0);
      a1a[m] = *(const bfrag*)(ab + (m * 16 + la) * 128 + (c0 ^ 64));
    }
#pragma unroll
    for (int n = 0; n < 3; ++n) {
      const int r = wc * 48 + n * 16 + la;
      b0[n] = *(const bfrag*)(bb + (r >> 6) * 8192 + (r & 63) * 128 + c0);
    }
    stageB(kt1, buf ^ 1, 0);
    stageB(kt1, buf ^ 1, 1);
    __builtin_amdgcn_s_barrier();
    asm volatile("s_waitcnt lgkmcnt(0)" ::: "memory");
    __builtin_amdgcn_sched_barrier(0);
    __builtin_amdgcn_s_setprio(1);
#pragma unroll
    for (int m = 0; m < 4; ++m)
#pragma unroll
      for (int n = 0; n < 3; ++n)
        acc[m][n] = __builtin_amdgcn_mfma_f32_16x16x32_bf16(a0[m], b0[n], acc[m][n], 0, 0, 0);
    __builtin_amdgcn_s_setprio(0);
    __builtin_amdgcn_s_barrier();

    // ---- P2: read a(m4-7,k0), a(m4-7,k1); stage B(kt+1) third 2
#pragma unroll
    for (int m = 0; m < 4; ++m) {
      a2[m]  = *(const bfrag*)(ab + ((m + 4) * 16 + la) * 128 + c0);
      a1b[m] = *(const bfrag*)(ab + ((m + 4) * 16 + la) * 128 + (c0 ^ 64));
    }
    stageB(kt1, buf ^ 1, 2);
    __builtin_amdgcn_s_barrier();
    asm volatile("s_waitcnt lgkmcnt(0)" ::: "memory");
    __builtin_amdgcn_sched_barrier(0);
    __builtin_amdgcn_s_setprio(1);
#pragma unroll
    for (int m = 0; m < 4; ++m)
#pragma unroll
      for (int n = 0; n < 3; ++n)
        acc[m + 4][n] = __builtin_amdgcn_mfma_f32_16x16x32_bf16(a2[m], b0[n], acc[m + 4][n], 0, 0, 0);
    __builtin_amdgcn_s_setprio(0);
    __builtin_amdgcn_s_barrier();

    // ---- P3: read b(k1); stage A(kt+2, current buf, half0)  [A reads drained @P2]
#pragma unroll
    for (int n = 0; n < 3; ++n) {
      const int r = wc * 48 + n * 16 + la;
      b1[n] = *(const bfrag*)(bb + (r >> 6) * 8192 + (r & 63) * 128 + (c0 ^ 64));
    }
    stageA(kt2, buf, 0);
    __builtin_amdgcn_s_barrier();
    asm volatile("s_waitcnt lgkmcnt(0)" ::: "memory");
    __builtin_amdgcn_sched_barrier(0);
    __builtin_amdgcn_s_setprio(1);
#pragma unroll
    for (int m = 0; m < 4; ++m)
#pragma unroll
      for (int n = 0; n < 3; ++n)
        acc[m][n] = __builtin_amdgcn_mfma_f32_16x16x32_bf16(a1a[m], b1[n], acc[m][n], 0, 0, 0);
    __builtin_amdgcn_s_setprio(0);
    __builtin_amdgcn_s_barrier();

    // ---- P4: stage A(kt+2, current buf, half1); counted vmcnt
    stageA(kt2, buf, 1);
    __builtin_amdgcn_s_barrier();
    __builtin_amdgcn_s_setprio(1);
#pragma unroll
    for (int m = 0; m < 4; ++m)
#pragma unroll
      for (int n = 0; n < 3; ++n)
        acc[m + 4][n] = __builtin_amdgcn_mfma_f32_16x16x32_bf16(a1b[m], b1[n], acc[m + 4][n], 0, 0, 0);
    __builtin_amdgcn_s_setprio(0);
    asm volatile("s_waitcnt vmcnt(4)" ::: "memory");
    __builtin_amdgcn_s_barrier();

    // ---- K=256 boundary: n-gate frags snapshot i_n -> in_lds, reset acc
    if (kt == 3) {
#pragma unroll
      for (int m = 0; m < 8; ++m)
#pragma unroll
        for (int n = 0; n < 3; ++n) {
          const int colb = wc * 48 + n * 16;
          if (colb >= 128) {                           // wave-uniform per n
            const int hl = (colb & 63) + la;
            const int row = wr * 128 + m * 16 + ls * 4;
            u32x2 v;
            v[0] = pack2bf(acc[m][n][0], acc[m][n][1]);
            v[1] = pack2bf(acc[m][n][2], acc[m][n][3]);
            *(u32x2*)(lds + 114688 + hl * 520 + row * 2) = v;
            acc[m][n] = (f32x4){0.f, 0.f, 0.f, 0.f};
          }
        }
    }
  }

  // =================== fused GRU epilogue ===================
  __syncthreads();                        // drains vmcnt(0): tail stages landed
  // dump pre-gates to LDS: pre[col][260] bf16 at byte col*520 + row*2
#pragma unroll
  for (int m = 0; m < 8; ++m)
#pragma unroll
    for (int n = 0; n < 3; ++n) {
      const int col = wc * 48 + n * 16 + la;
      const int row = wr * 128 + m * 16 + ls * 4;
      u32x2 v;
      v[0] = pack2bf(acc[m][n][0], acc[m][n][1]);
      v[1] = pack2bf(acc[m][n][2], acc[m][n][3]);
      *(u32x2*)(lds + col * 520 + row * 2) = v;
    }
  __syncthreads();

  const unsigned short* lu = (const unsigned short*)lds;
  const int row = t >> 1, half = t & 1;
  const int grow = brow + row;
  const int hbase = hb * 64 + half * 32;
  const float* h0p = (hb < 8) ? (ph + (size_t)grow * 512 + hbase)
                              : (enc + (size_t)grow * 512 + hbase - 512);
  float partial = 0.f;
  u16x4 st;
#pragma unroll
  for (int jj = 0; jj < 8; ++jj) {
    const int hg = hbase + jj * 4;
    const f32x4 br_ = *(const f32x4*)(bih + d * 3072 + hg);
    const f32x4 hr_ = *(const f32x4*)(bhh + d * 3072 + hg);
    const f32x4 bz_ = *(const f32x4*)(bih + d * 3072 + 1024 + hg);
    const f32x4 hz_ = *(const f32x4*)(bhh + d * 3072 + 1024 + hg);
    const f32x4 bn_ = *(const f32x4*)(bih + d * 3072 + 2048 + hg);
    const f32x4 hn_ = *(const f32x4*)(bhh + d * 3072 + 2048 + hg);
    const f32x4 wp_ = *(const f32x4*)(Wp + d * 1024 + hg);
    const f32x4 h0_ = *(const f32x4*)(h0p + jj * 4);
#pragma unroll
    for (int i = 0; i < 4; ++i) {
      const int hl = half * 32 + jj * 4 + i;
      const float rp = bf2f(lu[hl * 260 + row]);
      const float zp = bf2f(lu[(64 + hl) * 260 + row]);
      const float sp = bf2f(lu[(128 + hl) * 260 + row]);
      const float ip = bf2f(lu[57344 + hl * 260 + row]);
      const float r = fast_sigmoid(rp + br_[i] + hr_[i]);
      const float z = fast_sigmoid(zp + bz_[i] + hz_[i]);
      const float nn = fast_tanh(ip + bn_[i] + r * (sp + hn_[i]));
      const float hv = (1.f - z) * nn + z * h0_[i];
      st[i] = f2bf(hv);
      partial += hv * wp_[i];
    }
    *(u16x4*)(hn + (size_t)grow * 8192 + d * 1024 + hg) = st;
  }
  partial += __shfl_xor(partial, 1);
  if (!half) atomicAdd(pacc + (size_t)grow * 8 + d, partial);
}

// ---------------- 128x128 GEMM (m97 structure) — split-K hc ----------------
__global__ __launch_bounds__(256) void gemm_bt(
    const unsigned short* __restrict__ A, const unsigned short* __restrict__ Bt,
    float* __restrict__ out, int M, int N, int K, int kPerSlice)
{
  __shared__ unsigned short sA[128 * 32];
  __shared__ unsigned short sB[128 * 32];
  const int t = threadIdx.x;
  const int wave = t >> 6, lane = t & 63;
  const int wr = wave >> 1, wc = wave & 1;
  const int brow = blockIdx.y << 7;
  const int bcol = blockIdx.x << 7;
  const int kOff = blockIdx.z * kPerSlice;

  f32x4 acc[4][4];
#pragma unroll
  for (int m = 0; m < 4; m++)
#pragma unroll
    for (int n = 0; n < 4; n++) acc[m][n] = (f32x4){0.f, 0.f, 0.f, 0.f};

  const int srow = t >> 2;
  const int scol = (t & 3) << 3;
  const unsigned short* aSrc = A + (size_t)(brow + srow) * K + kOff + scol;
  const unsigned short* bSrc = Bt + (size_t)(bcol + srow) * K + kOff + scol;
  const size_t rowStep = (size_t)64 * K;
  unsigned short* dA0 = sA + wave * 512;
  unsigned short* dA1 = sA + 2048 + wave * 512;
  unsigned short* dB0 = sB + wave * 512;
  unsigned short* dB1 = sB + 2048 + wave * 512;

  const int la = lane & 15;
  const int lk = (lane >> 4) << 3;
  const int kSteps = kPerSlice >> 5;

  for (int ks = 0; ks < kSteps; ++ks) {
    load16(aSrc, dA0);
    load16(aSrc + rowStep, dA1);
    load16(bSrc, dB0);
    load16(bSrc + rowStep, dB1);
    aSrc += 32; bSrc += 32;
    __syncthreads();
    bfrag aF[4], bF[4];
#pragma unroll
    for (int m = 0; m < 4; m++)
      aF[m] = *(const bfrag*)&sA[(wr * 64 + m * 16 + la) * 32 + lk];
#pragma unroll
    for (int n = 0; n < 4; n++)
      bF[n] = *(const bfrag*)&sB[(wc * 64 + n * 16 + la) * 32 + lk];
#pragma unroll
    for (int m = 0; m < 4; m++)
#pragma unroll
      for (int n = 0; n < 4; n++)
        acc[m][n] = __builtin_amdgcn_mfma_f32_16x16x32_bf16(aF[m], bF[n], acc[m][n], 0, 0, 0);
    __syncthreads();
  }

  const int orow = brow + wr * 64 + (lane >> 4) * 4;
  const int ocol = bcol + wc * 64 + la;
  float* o = out + (size_t)blockIdx.z * ((size_t)M * N);
#pragma unroll
  for (int m = 0; m < 4; m++) {
    const int rb = orow + m * 16;
#pragma unroll
    for (int n = 0; n < 4; n++) {
      const int cb = ocol + n * 16;
#pragma unroll
      for (int r = 0; r < 4; r++)
        o[(size_t)(rb + r) * N + cb] = acc[m][n][r];
    }
  }
}

// ---------------- reduce split-K partials + bias + tanh -> h ----------------
__global__ __launch_bounds__(256) void reduce_h_kernel(
    const float* __restrict__ part, const float* __restrict__ b_h,
    float* __restrict__ hout)
{
  const int idx = blockIdx.x * 256 + threadIdx.x;
  const int kk = idx & 511;
  float s = 0.f;
#pragma unroll
  for (int sl = 0; sl < 16; ++sl) s += part[(size_t)sl * 1048576 + idx];
  float bias = 0.f;
#pragma unroll
  for (int d = 0; d < 8; ++d) bias += b_h[d * 512 + kk];
  hout[idx] = fast_tanh(s + bias);
}

// ---------------- probs finalize: sigmoid(acc + b_p) ----------------
__global__ __launch_bounds__(256) void probs_final(
    const float* __restrict__ pacc, const float* __restrict__ b_p,
    float* __restrict__ pout)
{
  const int i = blockIdx.x * 256 + threadIdx.x;   // 16384 total
  pout[i] = fast_sigmoid(pacc[i] + b_p[i & 7]);
}

extern "C" void kernel_launch(void* const* d_in, const int* in_sizes, int n_in,
                              void* d_out, int out_size, void* d_ws, size_t ws_size,
                              hipStream_t stream) {
  const float* x   = (const float*)d_in[0];
  const float* ph  = (const float*)d_in[1];
  const float* enc = (const float*)d_in[2];
  const float* Wih = (const float*)d_in[3];
  const float* Whh = (const float*)d_in[4];
  const float* bih = (const float*)d_in[5];
  const float* bhh = (const float*)d_in[6];
  const float* Wp  = (const float*)d_in[7];
  const float* bp  = (const float*)d_in[8];
  const float* Wh  = (const float*)d_in[9];
  const float* bh  = (const float*)d_in[10];
  float* out = (float*)d_out;
  char* ws = (char*)d_ws;

  unsigned short* A    = (unsigned short*)(ws + 0);           //  5.24 MB
  unsigned short* Bf   = (unsigned short*)(ws + 5242880);     // 62.91 MB
  unsigned short* BWh  = (unsigned short*)(ws + 68157440);    //  8.39 MB
  unsigned short* hn   = (unsigned short*)(ws + 76546048);    // 33.55 MB
  float*          part = (float*)(ws + 110100480);            // 67.11 MB (16 slices)
  float*          pacc = (float*)(ws + 177209344);            // 64 KB

  hipFuncSetAttribute((const void*)mega_gemm,
                      hipFuncAttributeMaxDynamicSharedMemorySize, 147968);

  hipMemsetAsync(pacc, 0, 2048 * 8 * sizeof(float), stream);

  pack_kernel<<<2048, 256, 0, stream>>>(x, ph, enc, Wih, Whh, Wh, A, Bf, BWh);

  mega_gemm<<<1024, 512, 147968, stream>>>(A, Bf, ph, enc, bih, bhh, Wp, hn, pacc);

  dim3 g3(HS_ / 128, B_ / 128, 16);
  gemm_bt<<<g3, 256, 0, stream>>>(hn, BWh, part, B_, HS_, 8192, 512);

  reduce_h_kernel<<<4096, 256, 0, stream>>>(part, bh, out);

  probs_final<<<64, 256, 0, stream>>>(pacc, bp, out + 1048576);
}